// Round 19
// baseline (97.993 us; speedup 1.0000x reference)
//
#include <hip/hip_runtime.h>
#include <math.h>

// Problem constants (ShowAttendTellCore)
//   B=1024, D_MODEL=512, N_HEADS=8, D_HEAD=64, N_LEVELS=4, N_POINTS=4
//   T_TOTAL=1920, RNN=512, ENC=512, ATT_HID=512
// Output layout (f32): h2 (524288) | h1 | h2 | c1 | c2   (total 2621440)

typedef __attribute__((ext_vector_type(8))) short          s16x8;
typedef __attribute__((ext_vector_type(8))) unsigned short u16x8;
typedef __attribute__((ext_vector_type(4))) float          f32x4;

#define LOG2E  1.4426950408889634f
#define LOG2E2 2.8853900817779268f

__device__ __forceinline__ float rcpf(float x) { return __builtin_amdgcn_rcpf(x); }
__device__ __forceinline__ float exp2f_fast(float x) { return __builtin_amdgcn_exp2f(x); }
__device__ __forceinline__ float sigf(float x) {
    return rcpf(1.0f + exp2f_fast(-x * LOG2E));
}
__device__ __forceinline__ float tanhf_fast(float x) {
    const float xc = fminf(fmaxf(x, -15.0f), 15.0f);
    const float e2 = exp2f_fast(xc * LOG2E2);
    return 1.0f - 2.0f * rcpf(e2 + 1.0f);
}
__device__ __forceinline__ unsigned short f2bf(float f) {   // RNE f32->bf16
    unsigned u = __float_as_uint(f);
    u += 0x7FFF + ((u >> 16) & 1);
    return (unsigned short)(u >> 16);
}
__device__ __forceinline__ float bf2f(unsigned short h) {
    return __uint_as_float(((unsigned)h) << 16);
}
// async global->LDS, 16B per lane
__device__ __forceinline__ void gld_lds16(const unsigned short* g, unsigned short* l) {
    __builtin_amdgcn_global_load_lds(
        (const __attribute__((address_space(1))) void*)g,
        (__attribute__((address_space(3))) void*)l, 16, 0, 0);
}

// ---------------- unified prep kernel: converts + transposes, ONE launch ---
// mode 0: strided f32->bf16 copy (x4 vec);   block = 1024 elems
// mode 1: same + LSTM gate row-interleave (row' = (r%512)*4 + r/512)
// mode 2: 32x32 tile transpose-convert (sld = src row width N_); src==nullptr
//         means zero-fill the tile region. block = one 32x32 tile.
struct PJob { const float* src; unsigned short* dst; int sld, dld, cols, nblk, mode; };
struct PJobs { PJob j[17]; };
__global__ __launch_bounds__(256) void prep(PJobs pj) {
    __shared__ float lds[32][33];
    int bid = blockIdx.x, ji = 0;
    while (bid >= pj.j[ji].nblk) { bid -= pj.j[ji].nblk; ++ji; }
    const PJob jb = pj.j[ji];
    const int t = threadIdx.x;
    if (jb.mode <= 1) {
        const int i = (bid * 256 + t) * 4;
        const int r = i / jb.cols, c = i - r * jb.cols;
        const int rd = jb.mode ? (((r & 511) << 2) | (r >> 9)) : r;
        const float4 v4 = *(const float4*)&jb.src[(size_t)r * jb.sld + c];
        ushort4 o;
        o.x = f2bf(v4.x); o.y = f2bf(v4.y); o.z = f2bf(v4.z); o.w = f2bf(v4.w);
        *(ushort4*)&jb.dst[(size_t)rd * jb.dld + c] = o;
    } else {
        const int tilesN = jb.sld >> 5;
        const int tn0 = (bid % tilesN) << 5, tk0 = (bid / tilesN) << 5;
        if (jb.src) {
#pragma unroll
            for (int q = 0; q < 4; ++q) {
                const int e = t + (q << 8);
                lds[e >> 5][e & 31] = jb.src[(size_t)(tk0 + (e >> 5)) * jb.sld + tn0 + (e & 31)];
            }
            __syncthreads();
#pragma unroll
            for (int q = 0; q < 4; ++q) {
                const int e = t + (q << 8);
                const int n = e >> 5, k = e & 31;
                jb.dst[(size_t)(tn0 + n) * jb.dld + tk0 + k] = f2bf(lds[k][n]);
            }
        } else {
#pragma unroll
            for (int q = 0; q < 4; ++q) {
                const int e = t + (q << 8);
                jb.dst[(size_t)(tn0 + (e >> 5)) * jb.dld + tk0 + (e & 31)] = 0;
            }
        }
    }
}

// ===== staged GEMMs; XOR chunk swizzle per rule #21 ========================

#define STAGE_T(buf, k0) do { \
        gld_lds16(Ag1 + (k0), &As[buf][s1 * 8]); \
        gld_lds16(Ag2 + (k0), &As[buf][s2 * 8]); \
        gld_lds16(Bg1 + (k0), &Bs[buf][s1 * 8]); \
        gld_lds16(Bg2 + (k0), &Bs[buf][s2 * 8]); } while (0)

// ---------------- 2-job staged GEMM (value + obat in ONE launch) -----------
// BM=BN=64, BK=64; C = A @ B^T + bias(3-piece select). 4-buf deep pipeline.
// Long-K job placed FIRST (dispatch-wave packing: 16-step blocks start in the
// first 256-block wave; 8-step value blocks fill the tail).
struct GJob { const unsigned short* A; int lda; const unsigned short* B; int ldb;
              const float* b0; const float* b1; const float* b2; int l0, l1;
              float* C; int ldc; int K; int nbx; int count; };
struct GJobs { GJob j[2]; };
__global__ __launch_bounds__(256) void sgemm2(GJobs gj) {
    __shared__ unsigned short As[4][64 * 64];
    __shared__ unsigned short Bs[4][64 * 64];

    int bid = blockIdx.x;
    GJob jb = gj.j[0];
    if (bid >= jb.count) { bid -= jb.count; jb = gj.j[1]; }
    const int bn = bid % jb.nbx, bm = bid / jb.nbx;
    const int lda = jb.lda, ldb = jb.ldb;

    const int tid = threadIdx.x;
    const int w = tid >> 6, lane = tid & 63;
    const int wr = w >> 1, wc = w & 1;
    const int lr = lane & 15, lg = lane >> 4;

    const int s1 = tid, s2 = tid + 256;
    const int r1 = s1 >> 3, c1 = ((s1 & 7) ^ (r1 & 7)) << 3;
    const int r2 = s2 >> 3, c2 = ((s2 & 7) ^ (r2 & 7)) << 3;
    const unsigned short* Ag1 = jb.A + (size_t)(bm * 64 + r1) * lda + c1;
    const unsigned short* Ag2 = jb.A + (size_t)(bm * 64 + r2) * lda + c2;
    const unsigned short* Bg1 = jb.B + (size_t)(bn * 64 + r1) * ldb + c1;
    const unsigned short* Bg2 = jb.B + (size_t)(bn * 64 + r2) * ldb + c2;

    f32x4 acc[2][2];
#pragma unroll
    for (int mt = 0; mt < 2; ++mt)
#pragma unroll
        for (int nt = 0; nt < 2; ++nt) acc[mt][nt] = (f32x4){0.f, 0.f, 0.f, 0.f};

    const int nsteps = jb.K >> 6;
    STAGE_T(0, 0);
    if (nsteps > 1) STAGE_T(1, 64);
    if (nsteps > 2) STAGE_T(2, 128);

    for (int t = 0; t < nsteps; ++t) {
        const int infl = nsteps - 1 - t;
        if (infl >= 2)      asm volatile("s_waitcnt vmcnt(8)" ::: "memory");
        else if (infl == 1) asm volatile("s_waitcnt vmcnt(4)" ::: "memory");
        else                asm volatile("s_waitcnt vmcnt(0)" ::: "memory");
        __builtin_amdgcn_s_barrier();
        if (t + 3 < nsteps) STAGE_T((t + 3) & 3, (t + 3) << 6);
        const unsigned short* Ab = &As[t & 3][0];
        const unsigned short* Bb = &Bs[t & 3][0];
        s16x8 a[2][2], bfr[2][2];
#pragma unroll
        for (int mt = 0; mt < 2; ++mt) {
            const int ar = wr * 32 + mt * 16 + lr;
#pragma unroll
            for (int ks = 0; ks < 2; ++ks)
                a[mt][ks] = *(const s16x8*)&Ab[(ar * 8 + ((ks * 4 + lg) ^ (ar & 7))) * 8];
        }
#pragma unroll
        for (int nt = 0; nt < 2; ++nt) {
            const int br = wc * 32 + nt * 16 + lr;
#pragma unroll
            for (int ks = 0; ks < 2; ++ks)
                bfr[nt][ks] = *(const s16x8*)&Bb[(br * 8 + ((ks * 4 + lg) ^ (br & 7))) * 8];
        }
#pragma unroll
        for (int ks = 0; ks < 2; ++ks)
#pragma unroll
            for (int mt = 0; mt < 2; ++mt)
#pragma unroll
                for (int nt = 0; nt < 2; ++nt)
                    acc[mt][nt] = __builtin_amdgcn_mfma_f32_16x16x32_bf16(
                        a[mt][ks], bfr[nt][ks], acc[mt][nt], 0, 0, 0);
    }
#pragma unroll
    for (int nt = 0; nt < 2; ++nt) {
        const int col = bn * 64 + wc * 32 + nt * 16 + lr;
        float bb;
        if (col < jb.l0)      bb = jb.b0[col];
        else if (col < jb.l1) bb = jb.b1[col - jb.l0];
        else                  bb = jb.b2[col - jb.l1];
#pragma unroll
        for (int mt = 0; mt < 2; ++mt) {
            const int rbase = bm * 64 + wr * 32 + mt * 16 + lg * 4;
#pragma unroll
            for (int r = 0; r < 4; ++r)
                jb.C[(size_t)(rbase + r) * jb.ldc + col] = acc[mt][nt][r] + bb;
        }
    }
}
#undef STAGE_T

// ---------------- split-K2 partial GEMM for LSTM gates ---------------------
// BM=64 BN=128 (wave 32x64, acc 2x4) -> 0.75 KB LDS-read per MFMA (LDS-BW-
// bound fix, R18: -8us). Grid 512 (2 blocks/CU, 72KB LDS). 3-buf, counted
// vmcnt(6) depth-2. XCD-chunked bijective swizzle on [0,512).
__global__ __launch_bounds__(256) void sgemm_ks(
    const unsigned short* __restrict__ A, int lda,
    const unsigned short* __restrict__ B, int ldb,
    unsigned short* __restrict__ gp0, unsigned short* __restrict__ gp1,
    int Kslice)
{
    __shared__ unsigned short As[3][64 * 64];    // 8KB x3
    __shared__ unsigned short Bs[3][128 * 64];   // 16KB x3  (72KB total)

    const int cb = ((blockIdx.x & 7) << 6) | (blockIdx.x >> 3);  // bijective [0,512)
    const int slice = cb >> 8;
    const int rblk  = cb & 255;
    const int bn = rblk & 15, bm = rblk >> 4;    // bn: 16 x 128 cols, bm: 16 x 64 rows
    const int koff = slice * Kslice;
    unsigned short* Cp = slice ? gp1 : gp0;

    const int tid = threadIdx.x;
    const int w = tid >> 6, lane = tid & 63;
    const int wr = w >> 1, wc = w & 1;
    const int lr = lane & 15, lg = lane >> 4;

    const int s1 = tid, s2 = tid + 256, s3 = tid + 512, s4 = tid + 768;
    const int ra1 = s1 >> 3, ca1 = ((s1 & 7) ^ (ra1 & 7)) << 3;
    const int ra2 = s2 >> 3, ca2 = ((s2 & 7) ^ (ra2 & 7)) << 3;
    const int rb3 = s3 >> 3, cb3 = ((s3 & 7) ^ (rb3 & 7)) << 3;
    const int rb4 = s4 >> 3, cb4 = ((s4 & 7) ^ (rb4 & 7)) << 3;
    const unsigned short* Ag1 = A + (size_t)(bm * 64 + ra1) * lda + koff + ca1;
    const unsigned short* Ag2 = A + (size_t)(bm * 64 + ra2) * lda + koff + ca2;
    const unsigned short* Bg1 = B + (size_t)(bn * 128 + ra1) * ldb + koff + ca1;
    const unsigned short* Bg2 = B + (size_t)(bn * 128 + ra2) * ldb + koff + ca2;
    const unsigned short* Bg3 = B + (size_t)(bn * 128 + rb3) * ldb + koff + cb3;
    const unsigned short* Bg4 = B + (size_t)(bn * 128 + rb4) * ldb + koff + cb4;

#define STAGE_K(buf, k0) do { \
        gld_lds16(Ag1 + (k0), &As[buf][s1 * 8]); \
        gld_lds16(Ag2 + (k0), &As[buf][s2 * 8]); \
        gld_lds16(Bg1 + (k0), &Bs[buf][s1 * 8]); \
        gld_lds16(Bg2 + (k0), &Bs[buf][s2 * 8]); \
        gld_lds16(Bg3 + (k0), &Bs[buf][s3 * 8]); \
        gld_lds16(Bg4 + (k0), &Bs[buf][s4 * 8]); } while (0)

    f32x4 acc[2][4];
#pragma unroll
    for (int mt = 0; mt < 2; ++mt)
#pragma unroll
        for (int nt = 0; nt < 4; ++nt) acc[mt][nt] = (f32x4){0.f, 0.f, 0.f, 0.f};

    const int nsteps = Kslice >> 6;
    STAGE_K(0, 0);
    if (nsteps > 1) STAGE_K(1, 64);

    for (int t = 0; t < nsteps; ++t) {
        const int infl = nsteps - 1 - t;
        if (infl >= 1) asm volatile("s_waitcnt vmcnt(6)" ::: "memory");
        else           asm volatile("s_waitcnt vmcnt(0)" ::: "memory");
        __builtin_amdgcn_s_barrier();
        if (t + 2 < nsteps) {
            const int bw = (t + 2) % 3;
            STAGE_K(bw, (t + 2) << 6);
        }
        const unsigned short* Ab = &As[t % 3][0];
        const unsigned short* Bb = &Bs[t % 3][0];
        s16x8 a[2][2], bfr[4][2];
#pragma unroll
        for (int mt = 0; mt < 2; ++mt) {
            const int ar = wr * 32 + mt * 16 + lr;
#pragma unroll
            for (int ks = 0; ks < 2; ++ks)
                a[mt][ks] = *(const s16x8*)&Ab[(ar * 8 + ((ks * 4 + lg) ^ (ar & 7))) * 8];
        }
#pragma unroll
        for (int nt = 0; nt < 4; ++nt) {
            const int br = wc * 64 + nt * 16 + lr;
#pragma unroll
            for (int ks = 0; ks < 2; ++ks)
                bfr[nt][ks] = *(const s16x8*)&Bb[(br * 8 + ((ks * 4 + lg) ^ (br & 7))) * 8];
        }
#pragma unroll
        for (int ks = 0; ks < 2; ++ks)
#pragma unroll
            for (int mt = 0; mt < 2; ++mt)
#pragma unroll
                for (int nt = 0; nt < 4; ++nt)
                    acc[mt][nt] = __builtin_amdgcn_mfma_f32_16x16x32_bf16(
                        a[mt][ks], bfr[nt][ks], acc[mt][nt], 0, 0, 0);
    }
#undef STAGE_K
#pragma unroll
    for (int nt = 0; nt < 4; ++nt) {
        const int col = bn * 128 + wc * 64 + nt * 16 + lr;
#pragma unroll
        for (int mt = 0; mt < 2; ++mt) {
            const int rbase = bm * 64 + wr * 32 + mt * 16 + lg * 4;
#pragma unroll
            for (int r = 0; r < 4; ++r)
                Cp[(size_t)(rbase + r) * 2048 + col] = f2bf(acc[mt][nt][r]);
        }
    }
}

// ---------------- split-K reduce + LSTM activation -------------------------
__global__ __launch_bounds__(256) void red_lstm(
    const unsigned short* __restrict__ g0, const unsigned short* __restrict__ g1,
    const float* __restrict__ c_in,
    float* __restrict__ h_a, float* __restrict__ h_b,
    unsigned short* __restrict__ hbf, int hbf_ld,
    float* __restrict__ c_out)
{
    const int id = blockIdx.x * 256 + threadIdx.x;   // row*512 + u
    const int row = id >> 9, u = id & 511;
    const size_t off = (size_t)row * 2048 + u * 4;
    const ushort4 p0 = *(const ushort4*)&g0[off];
    const ushort4 p1 = *(const ushort4*)&g1[off];
    const float gi = bf2f(p0.x) + bf2f(p1.x);
    const float gf = bf2f(p0.y) + bf2f(p1.y);
    const float gg = bf2f(p0.z) + bf2f(p1.z);
    const float go = bf2f(p0.w) + bf2f(p1.w);
    const float c  = c_in[id];
    const float c2 = sigf(gf) * c + sigf(gi) * tanhf_fast(gg);
    const float h2 = sigf(go) * tanhf_fast(c2);
    h_a[id] = h2;
    if (h_b) h_b[id] = h2;
    if (hbf) hbf[(size_t)row * hbf_ld + u] = f2bf(h2);
    c_out[id] = c2;
}

// ---------------- fused deformable sampling + context attention ------------
// Head-split: 2048 blocks x 256 thr, 4 heads/block (R15-proven).
// R19: nt loop unroll 2 (was disable): 2 in-flight Wb loads hide L2 latency
// under the 8-MFMA + 32-tanh body; VGPR headroom ample at 256 thr (~64+10
// vs 128 cap), spill tripwire = WRITE_SIZE.
__global__ __launch_bounds__(256, 4) void fused_att(
    const float* __restrict__ v,       // (1920, 512)
    const float* __restrict__ obat,    // (B, 768) [off|aw|atth]
    const float* __restrict__ refp,    // (B, 4)
    const int*   __restrict__ shapes,  // (4,)
    const int*   __restrict__ starts,  // (4,)
    const unsigned short* __restrict__ Wb,  // (512, 64) bf16, = Wctx^T
    const float* __restrict__ bctx,    // (512,)
    const float* __restrict__ walpha,  // (512,)
    unsigned short* __restrict__ attdst)    // bf16, row stride 2048
{
    __shared__ unsigned short cf[64 * 64];    // 8 KB, XOR chunk-swizzled
    __shared__ float ba[512];
    __shared__ float wal[512];
    __shared__ float awb[64];
    __shared__ float dsum[64];
    __shared__ float dots4[4][64];

    const int b   = blockIdx.x >> 1;
    const int hh  = blockIdx.x & 1;
    const int tid = threadIdx.x;

    if (tid < 64) awb[tid] = obat[b * 768 + 128 + hh * 64 + tid];
    __syncthreads();
    if (tid < 4) {
        float mx = -1e30f;
        for (int i = 0; i < 16; ++i) mx = fmaxf(mx, awb[tid * 16 + i]);
        float sum = 0.f;
        for (int i = 0; i < 16; ++i) { float e = exp2f_fast((awb[tid * 16 + i] - mx) * LOG2E); awb[tid * 16 + i] = e; sum += e; }
        float inv = rcpf(sum);
        for (int i = 0; i < 16; ++i) awb[tid * 16 + i] *= inv;
    }
    __syncthreads();

    ba[tid]        = bctx[tid]       + obat[b * 768 + 256 + tid];
    ba[tid + 256]  = bctx[tid + 256] + obat[b * 768 + 512 + tid];
    wal[tid]       = walpha[tid];
    wal[tid + 256] = walpha[tid + 256];
    {
        const int pl  = tid >> 2;
        const int sub = tid & 3;
        const int d0  = sub * 16;
        const int pg  = hh * 64 + pl;
        const int h   = pg >> 4;
        const int l   = (pg & 15) >> 2;
        const int Tlen = shapes[l];
        const int st   = starts[l];
        const float T  = (float)Tlen;
        const float refv = refp[b * 4 + l];
        const float offv = obat[b * 768 + pg];
        const float awv  = awb[pl];
        const float x   = (refv + offv * rcpf(T)) * T - 0.5f;  // exact: T is 2^k
        const float x0f = floorf(x);
        const float w1  = x - x0f;
        const int   x0  = (int)x0f;
        const float w0s = (x0 >= 0 && x0 < Tlen) ? (1.0f - w1) : 0.0f;
        const float w1s = (x0 + 1 >= 0 && x0 + 1 < Tlen) ? w1 : 0.0f;
        const int i0 = (min(max(x0, 0), Tlen - 1) + st) * 512 + h * 64;
        const int i1 = (min(max(x0 + 1, 0), Tlen - 1) + st) * 512 + h * 64;
        u16x8 o0, o1;
#pragma unroll
        for (int q = 0; q < 4; ++q) {
            const float4 a  = *(const float4*)&v[i0 + d0 + q * 4];
            const float4 bq = *(const float4*)&v[i1 + d0 + q * 4];
            unsigned short e0 = f2bf((a.x * w0s + bq.x * w1s) * awv);
            unsigned short e1 = f2bf((a.y * w0s + bq.y * w1s) * awv);
            unsigned short e2 = f2bf((a.z * w0s + bq.z * w1s) * awv);
            unsigned short e3 = f2bf((a.w * w0s + bq.w * w1s) * awv);
            if (q == 0) { o0[0] = e0; o0[1] = e1; o0[2] = e2; o0[3] = e3; }
            if (q == 1) { o0[4] = e0; o0[5] = e1; o0[6] = e2; o0[7] = e3; }
            if (q == 2) { o1[0] = e0; o1[1] = e1; o1[2] = e2; o1[3] = e3; }
            if (q == 3) { o1[4] = e0; o1[5] = e1; o1[6] = e2; o1[7] = e3; }
        }
        const int c0 = (sub * 2)     ^ (pl & 7);
        const int c1 = (sub * 2 + 1) ^ (pl & 7);
        *(u16x8*)&cf[pl * 64 + c0 * 8] = o0;
        *(u16x8*)&cf[pl * 64 + c1 * 8] = o1;
    }
    __syncthreads();

    {
        const int wn   = tid >> 6, lane = tid & 63;
        const int lr   = lane & 15, lg = lane >> 4;

        s16x8 afrag[4][2];
#pragma unroll
        for (int mt = 0; mt < 4; ++mt) {
            const int row = mt * 16 + lr;
#pragma unroll
            for (int ks = 0; ks < 2; ++ks) {
                const int ch = (ks * 4 + lg) ^ (row & 7);
                afrag[mt][ks] = *(const s16x8*)&cf[row * 64 + ch * 8];
            }
        }
        f32x4 part[4];
#pragma unroll
        for (int mt = 0; mt < 4; ++mt) part[mt] = (f32x4){0.f, 0.f, 0.f, 0.f};

#pragma unroll 2
        for (int nt = 0; nt < 8; ++nt) {
            const int col = (wn * 8 + nt) * 16 + lr;
            const s16x8 b0 = *(const s16x8*)&Wb[col * 64 + lg * 8];
            const s16x8 b1 = *(const s16x8*)&Wb[col * 64 + 32 + lg * 8];
            const float bav = ba[col], wav = wal[col];
#pragma unroll
            for (int mt = 0; mt < 4; ++mt) {
                f32x4 acc = {0.f, 0.f, 0.f, 0.f};
                acc = __builtin_amdgcn_mfma_f32_16x16x32_bf16(afrag[mt][0], b0, acc, 0, 0, 0);
                acc = __builtin_amdgcn_mfma_f32_16x16x32_bf16(afrag[mt][1], b1, acc, 0, 0, 0);
#pragma unroll
                for (int r = 0; r < 4; ++r)
                    part[mt][r] += tanhf_fast(acc[r] + bav) * wav;
            }
        }
#pragma unroll
        for (int mt = 0; mt < 4; ++mt) {
#pragma unroll
            for (int r = 0; r < 4; ++r) {
                float s = part[mt][r];
                s += __shfl_xor(s, 1); s += __shfl_xor(s, 2);
                s += __shfl_xor(s, 4); s += __shfl_xor(s, 8);
                if (lr == 0) dots4[wn][mt * 16 + lg * 4 + r] = s;
            }
        }
    }
    __syncthreads();
    if (tid < 64)
        dsum[tid] = dots4[0][tid] + dots4[1][tid] + dots4[2][tid] + dots4[3][tid];
    __syncthreads();

    if (tid < 4) {
        float mx = -1e30f;
        for (int i = 0; i < 16; ++i) mx = fmaxf(mx, dsum[tid * 16 + i]);
        float sum = 0.f;
        for (int i = 0; i < 16; ++i) { float e = exp2f_fast((dsum[tid * 16 + i] - mx) * LOG2E); dsum[tid * 16 + i] = e; sum += e; }
        float inv = rcpf(sum);
        for (int i = 0; i < 16; ++i) dsum[tid * 16 + i] *= inv;
    }
    __syncthreads();

    {
        const int hl = tid >> 6, d = tid & 63;
        const int ch = d >> 3, e = d & 7;
        float s = 0.f;
#pragma unroll
        for (int p = 0; p < 16; ++p) {
            const int row = hl * 16 + p;
            s += dsum[hl * 16 + p] * bf2f(cf[row * 64 + ((ch ^ (row & 7)) * 8) + e]);
        }
        attdst[(size_t)b * 2048 + hh * 256 + tid] = f2bf(s);
    }
}

extern "C" void kernel_launch(void* const* d_in, const int* in_sizes, int n_in,
                              void* d_out, int out_size, void* d_ws, size_t ws_size,
                              hipStream_t stream) {
    const float* xt     = (const float*)d_in[0];
    const float* h0     = (const float*)d_in[1];   // (2,1024,512)
    const float* c0     = (const float*)d_in[2];
    const float* query  = (const float*)d_in[3];   // (1,1024,512)
    const float* refp   = (const float*)d_in[4];   // (1,1024,4,1)
    const float* inflat = (const float*)d_in[5];   // (1,1920,512)
    const int*   shapes = (const int*)d_in[6];
    const int*   starts = (const int*)d_in[7];
    const float* Wv     = (const float*)d_in[9];   // (512,512) (K,N)
    const float* bv     = (const float*)d_in[10];
    const float* Woff   = (const float*)d_in[11];  // (1024,128) (K,N)
    const float* boff   = (const float*)d_in[12];
    const float* Wattw  = (const float*)d_in[13];  // (1024,128)
    const float* battw  = (const float*)d_in[14];
    const float* Wctx   = (const float*)d_in[15];  // (64,512)
    const float* bctx   = (const float*)d_in[16];
    const float* Wh2a   = (const float*)d_in[17];  // (512,512) (K,N)
    const float* bh2a   = (const float*)d_in[18];
    const float* walpha = (const float*)d_in[19];
    const float* Wih0   = (const float*)d_in[21];  // (2048,1536) (N,K)
    const float* Whh0   = (const float*)d_in[22];  // (2048,512)
    const float* Wih1   = (const float*)d_in[23];  // (2048,512)
    const float* Whh1   = (const float*)d_in[24];  // (2048,512)

    float* out = (float*)d_out;
    float* ws  = (float*)d_ws;

    // ws layout (f32 units), lifetime-overlapped
    float*          v     = ws;                                   // 983040
    float*          obat  = ws + 983040;                          // 1024x768 [off|aw|atth]
    unsigned short* Acat  = (unsigned short*)(ws + 1769472);      // 1024x2048 bf16
    unsigned short* Bcat0 = (unsigned short*)(ws + 2818048);      // 2048x2048 bf16 (gate-ilv)
    unsigned short* Ainf  = (unsigned short*)(ws + 4915200);      // 1920x512 bf16
    unsigned short* Wvt   = (unsigned short*)(ws + 5406720);      // 512x512 bf16
    unsigned short* Wcat  = (unsigned short*)(ws + 5537792);      // 768x1024 bf16
    unsigned short* Ahq   = (unsigned short*)(ws + 5931008);      // 1024x1024 bf16
    unsigned short* Wb    = (unsigned short*)(ws + 6455296);      // 512x64 bf16 (Wctx^T)
    unsigned short* Ag1   = (unsigned short*)(ws + 7012352);      // 1024x1024 bf16
    unsigned short* Bcat1 = (unsigned short*)(ws + 7536640);      // 2048x1024 bf16 (gate-ilv)
    // split-K partial buffers (bf16 1024x2048 each), in DEAD regions at use
    unsigned short* gp0 = (unsigned short*)ws;                    // ws+0 .. +1048576
    unsigned short* gp1 = (unsigned short*)(ws + 4915200);        // .. +5963776

    const float* h00    = h0;
    const float* h_last = h0 + 524288;     // h0[1]
    float* h1  = out + 524288;             // h_new[0]
    float* c1  = out + 1572864;            // c_new[0]
    float* h2a = out;                      // first output
    float* h2b = out + 1048576;            // h_new[1]
    float* c2  = out + 2097152;            // c_new[1]

    // --- prep: all converts + transposes + zero-pad in ONE launch -----------
    { PJobs pj;
      pj.j[0]  = { xt,      Acat,          512,  2048, 512,  512,  0 };
      pj.j[1]  = { query,   Acat + 1024,   512,  2048, 512,  512,  0 };
      pj.j[2]  = { h00,     Acat + 1536,   512,  2048, 512,  512,  0 };
      pj.j[3]  = { h_last,  Ahq,           512,  1024, 512,  512,  0 };
      pj.j[4]  = { query,   Ahq + 512,     512,  1024, 512,  512,  0 };
      pj.j[5]  = { h_last,  Ag1 + 512,     512,  1024, 512,  512,  0 };
      pj.j[6]  = { Wih0,    Bcat0,         1536, 2048, 1536, 3072, 1 };
      pj.j[7]  = { Whh0,    Bcat0 + 1536,  512,  2048, 512,  1024, 1 };
      pj.j[8]  = { Wih1,    Bcat1,         512,  1024, 512,  1024, 1 };
      pj.j[9]  = { Whh1,    Bcat1 + 512,   512,  1024, 512,  1024, 1 };
      pj.j[10] = { inflat,  Ainf,          512,  512,  512,  960,  0 };
      pj.j[11] = { Wv,      Wvt,                     512, 512,  512, 256, 2 };
      pj.j[12] = { Woff,    Wcat,                    128, 1024, 1024, 128, 2 };
      pj.j[13] = { Wattw,   Wcat + 128 * 1024,       128, 1024, 1024, 128, 2 };
      pj.j[14] = { Wh2a,    Wcat + 256 * 1024,       512, 1024, 512, 256, 2 };
      pj.j[15] = { Wctx,    Wb,                      512, 64,   64,  32,  2 };
      pj.j[16] = { nullptr, Wcat + 256 * 1024 + 512, 512, 1024, 512, 256, 2 };
      prep<<<11232, 256, 0, stream>>>(pj); }

    // --- value + obat GEMMs fused into ONE launch (432 blocks) --------------
    // Long-K obat job first: 16-step blocks fill the first dispatch wave,
    // 8-step value blocks pack the tail.
    { GJobs gj;
      gj.j[0] = { Ahq,  1024, Wcat, 1024, boff, battw, bh2a, 128, 256,
                  obat, 768, 1024, 12, 192 };   // 1024x768: [boff|battw|bh2a]
      gj.j[1] = { Ainf, 512,  Wvt,  512,  bv,   bv,    bv,   0,   0,
                  v,    512, 512,  8,  240 };   // 1920x512: all cols -> bv[col]
      sgemm2<<<432, 256, 0, stream>>>(gj); }

    // --- fused deformable sampling + context attention (writes Acat[:,512:1024]) ---
    fused_att<<<2048, 256, 0, stream>>>(v, obat, refp, shapes, starts,
                                        Wb, bctx, walpha, Acat + 512);

    // LSTM0: split-K2 partials (BN=128 tiles, XCD-swizzled) + fused reduce/act
    sgemm_ks<<<512, 256, 0, stream>>>(Acat, 2048, Bcat0, 2048, gp0, gp1, 1024);
    red_lstm<<<2048, 256, 0, stream>>>(gp0, gp1, c0, h1, nullptr, Ag1, 1024, c1);
    // LSTM1: split-K2 partials + reduce/act (h2 -> out0 and h_new[1])
    sgemm_ks<<<512, 256, 0, stream>>>(Ag1, 1024, Bcat1, 1024, gp0, gp1, 512);
    red_lstm<<<2048, 256, 0, stream>>>(gp0, gp1, c0 + 524288, h2a, h2b, nullptr, 0, c2);
}